// Round 6
// baseline (716.756 us; speedup 1.0000x reference)
//
#include <hip/hip_runtime.h>
#include <stdint.h>

// N=16384 points, K=10 (fixed by setup_inputs).
#define NPTS   16384
#define TOPK   10
#define NCOL   128
#define NROW   128
#define NCELL  (NCOL * NROW)
#define XMIN   (-5.0f)
#define CW     (0.078125f)
#define INVW   (12.8f)
#define MASK14 0xFFFFC000u

// ws layout (bytes), [0,131328) zeroed by one memset:
//   0      accum[4] floats; 16 ticket uint
//   256    hist[NCELL] uint
//   65792  cnt[NCELL] uint
//   131328 base[NCELL+1] uint
//   196992 cid[NPTS] int
//   262528 sorted[NPTS] float4 (x,y,z,opacity), (bx,by)-row-major order

__device__ __forceinline__ unsigned umin_(unsigned a, unsigned b) { return a < b ? a : b; }
__device__ __forceinline__ unsigned umax_(unsigned a, unsigned b) { return a > b ? a : b; }

__device__ __forceinline__ void chain_insert(unsigned (&a)[TOPK], unsigned key) {
#pragma unroll
    for (int k = TOPK - 1; k > 0; --k) a[k] = umin_(umax_(a[k - 1], key), a[k]);
    a[0] = umin_(a[0], key);
}

// ---- fused trivial losses + cell histogram --------------------------------
__global__ __launch_bounds__(256) void setup_kernel(
    const float* __restrict__ pos, const float* __restrict__ opac,
    const float* __restrict__ scales, float* __restrict__ accum,
    unsigned* __restrict__ hist, int* __restrict__ cid)
{
    int i = blockIdx.x * 256 + threadIdx.x;
    float o = opac[i];
    float d = o - 0.5f;
    float s_sp = fabsf(o);
    float s_op = d * d;
    float s_sc = fabsf(scales[3 * i] - 1.0f) + fabsf(scales[3 * i + 1] - 1.0f)
               + fabsf(scales[3 * i + 2] - 1.0f);
    float x = pos[3 * i], y = pos[3 * i + 1];
    int bx = min(max((int)((x - XMIN) * INVW), 0), NCOL - 1);
    int by = min(max((int)((y - XMIN) * INVW), 0), NROW - 1);
    int c = bx * NROW + by;
    cid[i] = c;
    atomicAdd(&hist[c], 1u);
#pragma unroll
    for (int off = 32; off > 0; off >>= 1) {
        s_sp += __shfl_down(s_sp, off, 64);
        s_sc += __shfl_down(s_sc, off, 64);
        s_op += __shfl_down(s_op, off, 64);
    }
    if ((threadIdx.x & 63) == 0) {
        atomicAdd(&accum[0], s_sp);
        atomicAdd(&accum[1], s_sc);
        atomicAdd(&accum[2], s_op);
    }
}

// ---- exclusive prefix over 16384 cells, 2 barriers ------------------------
__global__ __launch_bounds__(1024) void prefix_cells(
    const unsigned* __restrict__ hist, unsigned* __restrict__ base)
{
    __shared__ unsigned bs[16];
    const int t = threadIdx.x, lane = t & 63, wv = t >> 6;
    unsigned loc[16];
    unsigned run = 0;
#pragma unroll
    for (int k = 0; k < 16; ++k) { loc[k] = hist[t * 16 + k]; run += loc[k]; }
    unsigned inc = run;
#pragma unroll
    for (int off = 1; off < 64; off <<= 1) {
        unsigned v = (unsigned)__shfl_up((int)inc, off, 64);
        if (lane >= off) inc += v;
    }
    if (lane == 63) bs[wv] = inc;
    __syncthreads();
    if (t < 16) {
        unsigned v = bs[t];
        unsigned iv = v;
#pragma unroll
        for (int off = 1; off < 16; off <<= 1) {
            unsigned u = (unsigned)__shfl_up((int)iv, off, 64);
            if (t >= off) iv += u;
        }
        bs[t] = iv - v;   // exclusive wave offset
    }
    __syncthreads();
    unsigned acc = bs[wv] + inc - run;
#pragma unroll
    for (int k = 0; k < 16; ++k) { base[t * 16 + k] = acc; acc += loc[k]; }
    if (t == 1023) base[NCELL] = acc;
}

__global__ __launch_bounds__(256) void scatter_sorted(
    const float* __restrict__ pos, const float* __restrict__ opac,
    const int* __restrict__ cid, const unsigned* __restrict__ base,
    unsigned* __restrict__ cnt, float4* __restrict__ sorted)
{
    int i = blockIdx.x * 256 + threadIdx.x;
    int c = cid[i];
    unsigned p = base[c] + atomicAdd(&cnt[c], 1u);
    sorted[p] = make_float4(pos[3 * i], pos[3 * i + 1], pos[3 * i + 2], opac[i]);
}

// ---- fused exact KNN + smoothness + final combine -------------------------
// One block = 2 waves = the same 64 consecutive sorted points (lane L of both
// waves owns point gbase+L). Bound pass over a 256-index window (split across
// waves), then disjoint column scans: wave0 right (c>=c0), wave1 left (c<c0).
// Candidate runs are contiguous; streamed via LDS broadcast (R1's proven
// 87%-VALU loop shape). r_i tightens per column; exactness invariant:
// a[9] >= true d10 key at all times, so need-predicates are conservative.
__global__ __launch_bounds__(128) void knn_fused(
    const float4* __restrict__ sorted, const unsigned* __restrict__ cellbase,
    float* __restrict__ accum, unsigned* __restrict__ ticket,
    float* __restrict__ out)
{
    __shared__ float4 stage[2][64];
    __shared__ unsigned xch[2][64][TOPK];

    const int lane  = threadIdx.x & 63;
    const int wv    = threadIdx.x >> 6;
    const int gbase = blockIdx.x * 64;
    const int s     = gbase + lane;
    const float4 me = sorted[s];

    unsigned a[TOPK];
#pragma unroll
    for (int k = 0; k < TOPK; ++k) a[k] = 0xFFFFFFFFu;

    // ---- bound pass: wave-uniform 128-candidate half-window ----
    const int wstart = gbase - 96 + wv * 128;
#pragma unroll 4
    for (int t = 0; t < 128; ++t) {
        int pc = (wstart + t) & (NPTS - 1);
        float4 c = sorted[pc];
        float dx = c.x - me.x, dy = c.y - me.y, dz = c.z - me.z;
        float d2 = fmaf(dx, dx, fmaf(dy, dy, dz * dz));
        unsigned key = (__float_as_uint(d2) & MASK14) | (unsigned)pc;
        if (pc == s) key = 0xFFFFFFFFu;
        chain_insert(a, key);
    }
#pragma unroll
    for (int k = 0; k < TOPK; ++k) xch[wv][lane][k] = a[k];
    __syncthreads();
#pragma unroll
    for (int k = 0; k < TOPK; ++k) chain_insert(a, xch[wv ^ 1][lane][k]);

    // sentinel: strictly greater than every key of the true top-10
    const unsigned sent = (a[TOPK - 1] & MASK14) + 0x8000u;
#pragma unroll
    for (int k = 0; k < TOPK; ++k) a[k] = sent;
    float ri = sqrtf(__uint_as_float((sent & MASK14) + 0x4000u)) * 1.000001f;

    // ---- column scan ----
    int bxi = min(max((int)((me.x - XMIN) * INVW), 0), NCOL - 1);
    const int c0 = __builtin_amdgcn_readfirstlane(bxi);  // lane0 = min column
    int c    = wv ? (c0 - 1) : c0;
    const int step = wv ? -1 : 1;

    while (c >= 0 && c < NCOL) {
        float edge = XMIN + (wv ? (float)(c + 1) : (float)c) * CW;
        float dxm  = wv ? (me.x - edge) : (edge - me.x);   // min |dx| to column
        if (__ballot(dxm < ri) == 0ull) break;

        float ylo = me.y - ri, yhi = me.y + ri;
#pragma unroll
        for (int off = 1; off < 64; off <<= 1) {
            ylo = fminf(ylo, __shfl_xor(ylo, off, 64));
            yhi = fmaxf(yhi, __shfl_xor(yhi, off, 64));
        }
        int byl = min(max((int)((ylo - XMIN) * INVW), 0), NROW - 1);
        int byh = min(max((int)((yhi - XMIN) * INVW), 0), NROW - 1);
        byl = __builtin_amdgcn_readfirstlane(byl);
        byh = __builtin_amdgcn_readfirstlane(byh);
        const int lo = (int)cellbase[c * NROW + byl];
        const int hi = (int)cellbase[c * NROW + byh + 1];

        for (int p0 = lo; p0 < hi; p0 += 64) {
            const int n = min(64, hi - p0);
            stage[wv][lane] = sorted[min(p0 + lane, NPTS - 1)];
#pragma unroll 2
            for (int t = 0; t < n; ++t) {
                float4 cpt = stage[wv][t];
                float dx = cpt.x - me.x, dy = cpt.y - me.y, dz = cpt.z - me.z;
                float d2 = fmaf(dx, dx, fmaf(dy, dy, dz * dz));
                unsigned key = (__float_as_uint(d2) & MASK14) | (unsigned)(p0 + t);
                if (p0 + t == s) key = 0xFFFFFFFFu;
                chain_insert(a, key);
            }
        }
        // tighten the radius (monotone non-increasing; stays >= true r10)
        ri = sqrtf(__uint_as_float((a[TOPK - 1] & MASK14) + 0x4000u)) * 1.000001f;
        c += step;
    }

    // ---- cross-wave merge (disjoint column sets -> no duplicates) ----
    __syncthreads();
#pragma unroll
    for (int k = 0; k < TOPK; ++k) xch[wv][lane][k] = a[k];
    __syncthreads();

    if (wv == 0) {
#pragma unroll
        for (int k = 0; k < TOPK; ++k) chain_insert(a, xch[1][lane][k]);
        const float* w = (const float*)sorted;
        float v = 0.0f;
#pragma unroll
        for (int k = 0; k < TOPK; ++k) {
            int j = (int)(a[k] & 0x3FFFu);
            v += fabsf(me.w - w[4 * j + 3]);
        }
#pragma unroll
        for (int off = 32; off > 0; off >>= 1) v += __shfl_down(v, off, 64);
        if (lane == 0) atomicAdd(&accum[3], v);
    }

    __syncthreads();
    if (threadIdx.x == 0) {
        __threadfence();
        unsigned tk = atomicAdd(ticket, 1u);
        if (tk == gridDim.x - 1) {
            float sp = atomicAdd(&accum[0], 0.0f);
            float sc = atomicAdd(&accum[1], 0.0f);
            float op = atomicAdd(&accum[2], 0.0f);
            float sm = atomicAdd(&accum[3], 0.0f);
            const float n = (float)NPTS;
            out[0] = 0.01f * (sp / n) + 0.1f * (sm / (n * 10.0f))
                   + sc / (3.0f * n) + op / n;
        }
    }
}

extern "C" void kernel_launch(void* const* d_in, const int* in_sizes, int n_in,
                              void* d_out, int out_size, void* d_ws, size_t ws_size,
                              hipStream_t stream)
{
    const float* pos    = (const float*)d_in[0];
    const float* opac   = (const float*)d_in[1];
    const float* scales = (const float*)d_in[2];
    float* out = (float*)d_out;

    char* ws = (char*)d_ws;
    float*    accum  = (float*)ws;
    unsigned* ticket = (unsigned*)(ws + 16);
    unsigned* hist   = (unsigned*)(ws + 256);
    unsigned* cnt    = (unsigned*)(ws + 65792);
    unsigned* base   = (unsigned*)(ws + 131328);
    int*      cid    = (int*)(ws + 196992);
    float4*   sorted = (float4*)(ws + 262528);

    hipMemsetAsync(ws, 0, 131328, stream);   // accum, ticket, hist, cnt

    setup_kernel  <<<NPTS / 256, 256, 0, stream>>>(pos, opac, scales, accum, hist, cid);
    prefix_cells  <<<1, 1024, 0, stream>>>(hist, base);
    scatter_sorted<<<NPTS / 256, 256, 0, stream>>>(pos, opac, cid, base, cnt, sorted);
    knn_fused     <<<NPTS / 64, 128, 0, stream>>>(sorted, base, accum, ticket, out);
}

// Round 7
// 321.127 us; speedup vs baseline: 2.2320x; 2.2320x over previous
//
#include <hip/hip_runtime.h>
#include <stdint.h>

// N=16384 points, K=10 (fixed by setup_inputs).
#define NPTS   16384
#define TOPK   10
#define NCOL   128
#define NROW   128
#define NCELL  (NCOL * NROW)
#define XMIN   (-5.0f)
#define INVW   (12.8f)
#define MASK14 0xFFFFC000u
#define BOFF   224                 // bound window [gbase-224, gbase+288)

// ws layout (bytes), [0,131328) zeroed by one memset:
//   0      accum[4] floats; 16 ticket uint
//   256    hist[NCELL] uint
//   65792  cnt[NCELL] uint
//   131328 base[NCELL+1] uint
//   196992 cid[NPTS] int
//   262528 sorted[NPTS] float4 (x,y,z,opacity), (bx,by)-row-major order

__device__ __forceinline__ unsigned umin_(unsigned a, unsigned b) { return a < b ? a : b; }
__device__ __forceinline__ unsigned umax_(unsigned a, unsigned b) { return a > b ? a : b; }

__device__ __forceinline__ void chain_insert(unsigned (&a)[TOPK], unsigned key) {
#pragma unroll
    for (int k = TOPK - 1; k > 0; --k) a[k] = umin_(umax_(a[k - 1], key), a[k]);
    a[0] = umin_(a[0], key);
}

// ---- fused trivial losses + cell histogram --------------------------------
__global__ __launch_bounds__(256) void setup_kernel(
    const float* __restrict__ pos, const float* __restrict__ opac,
    const float* __restrict__ scales, float* __restrict__ accum,
    unsigned* __restrict__ hist, int* __restrict__ cid)
{
    int i = blockIdx.x * 256 + threadIdx.x;
    float o = opac[i];
    float d = o - 0.5f;
    float s_sp = fabsf(o);
    float s_op = d * d;
    float s_sc = fabsf(scales[3 * i] - 1.0f) + fabsf(scales[3 * i + 1] - 1.0f)
               + fabsf(scales[3 * i + 2] - 1.0f);
    float x = pos[3 * i], y = pos[3 * i + 1];
    int bx = min(max((int)((x - XMIN) * INVW), 0), NCOL - 1);
    int by = min(max((int)((y - XMIN) * INVW), 0), NROW - 1);
    int c = bx * NROW + by;
    cid[i] = c;
    atomicAdd(&hist[c], 1u);
#pragma unroll
    for (int off = 32; off > 0; off >>= 1) {
        s_sp += __shfl_down(s_sp, off, 64);
        s_sc += __shfl_down(s_sc, off, 64);
        s_op += __shfl_down(s_op, off, 64);
    }
    if ((threadIdx.x & 63) == 0) {
        atomicAdd(&accum[0], s_sp);
        atomicAdd(&accum[1], s_sc);
        atomicAdd(&accum[2], s_op);
    }
}

// ---- exclusive prefix over 16384 cells ------------------------------------
__global__ __launch_bounds__(1024) void prefix_cells(
    const unsigned* __restrict__ hist, unsigned* __restrict__ base)
{
    __shared__ unsigned bs[16];
    const int t = threadIdx.x, lane = t & 63, wv = t >> 6;
    unsigned loc[16];
    unsigned run = 0;
#pragma unroll
    for (int k = 0; k < 16; ++k) { loc[k] = hist[t * 16 + k]; run += loc[k]; }
    unsigned inc = run;
#pragma unroll
    for (int off = 1; off < 64; off <<= 1) {
        unsigned v = (unsigned)__shfl_up((int)inc, off, 64);
        if (lane >= off) inc += v;
    }
    if (lane == 63) bs[wv] = inc;
    __syncthreads();
    if (t < 16) {
        unsigned v = bs[t];
        unsigned iv = v;
#pragma unroll
        for (int off = 1; off < 16; off <<= 1) {
            unsigned u = (unsigned)__shfl_up((int)iv, off, 64);
            if (t >= off) iv += u;
        }
        bs[t] = iv - v;
    }
    __syncthreads();
    unsigned acc = bs[wv] + inc - run;
#pragma unroll
    for (int k = 0; k < 16; ++k) { base[t * 16 + k] = acc; acc += loc[k]; }
    if (t == 1023) base[NCELL] = acc;
}

__global__ __launch_bounds__(256) void scatter_sorted(
    const float* __restrict__ pos, const float* __restrict__ opac,
    const int* __restrict__ cid, const unsigned* __restrict__ base,
    unsigned* __restrict__ cnt, float4* __restrict__ sorted)
{
    int i = blockIdx.x * 256 + threadIdx.x;
    int c = cid[i];
    unsigned p = base[c] + atomicAdd(&cnt[c], 1u);
    sorted[p] = make_float4(pos[3 * i], pos[3 * i + 1], pos[3 * i + 2], opac[i]);
}

// ---- fused exact KNN: bound + column-window scan + merge + combine --------
// Block = 8 waves; every wave owns the SAME 64 consecutive sorted points
// (lane L <-> point gbase+L). Bound: 512-candidate window split 8x64.
// Main: block-uniform x-column rank window [LO,HI) split into 8 equal
// chunks; each wave streams its chunk via its private LDS stage row with
// the branchless sentinel-seeded chain (R1's proven loop shape).
__global__ __launch_bounds__(512) void knn_fused(
    const float4* __restrict__ sorted, const unsigned* __restrict__ cellbase,
    float* __restrict__ accum, unsigned* __restrict__ ticket,
    float* __restrict__ out)
{
    __shared__ float4 stage[8][64];
    __shared__ unsigned xch[8][64][TOPK];

    const int lane  = threadIdx.x & 63;
    const int wv    = threadIdx.x >> 6;
    const int gbase = blockIdx.x * 64;
    const int s     = gbase + lane;
    const float4 me = sorted[s];

    // ---- bound phase: 512-candidate window, 64 per wave ----
    unsigned a[TOPK];
#pragma unroll
    for (int k = 0; k < TOPK; ++k) a[k] = 0xFFFFFFFFu;
    const int bstart = gbase - BOFF + wv * 64;
#pragma unroll 4
    for (int t = 0; t < 64; ++t) {
        int pc = (bstart + t) & (NPTS - 1);        // distinct; wraps
        float4 c = sorted[pc];
        float dx = c.x - me.x, dy = c.y - me.y, dz = c.z - me.z;
        float d2 = fmaf(dx, dx, fmaf(dy, dy, dz * dz));
        unsigned key = (__float_as_uint(d2) & MASK14) | (unsigned)pc;
        if (pc == s) key = 0xFFFFFFFFu;
        chain_insert(a, key);
    }
#pragma unroll
    for (int k = 0; k < TOPK; ++k) xch[wv][lane][k] = a[k];
    __syncthreads();
#pragma unroll
    for (int w = 0; w < 8; ++w) {
        if (w == wv) continue;
#pragma unroll
        for (int k = 0; k < TOPK; ++k) chain_insert(a, xch[w][lane][k]);
    }
    const unsigned B = a[TOPK - 1];                 // valid upper bound key
    const unsigned sent = (B & MASK14) + 0x8000u;   // > every true-NN key
    const float ri = sqrtf(__uint_as_float((B & MASK14) + 0x4000u)) * 1.000001f;

    // ---- block-uniform column-rank window ----
    int bxl = min(max((int)((me.x - ri - XMIN) * INVW), 0), NCOL - 1);
    int bxh = min(max((int)((me.x + ri - XMIN) * INVW), 0), NCOL - 1);
    int lo = (int)cellbase[bxl * NROW];
    int hi = (int)cellbase[(bxh + 1) * NROW];
#pragma unroll
    for (int off = 1; off < 64; off <<= 1) {
        lo = min(lo, __shfl_xor(lo, off, 64));
        hi = max(hi, __shfl_xor(hi, off, 64));
    }
    const int LO  = __builtin_amdgcn_readfirstlane(lo);
    const int HI  = __builtin_amdgcn_readfirstlane(hi);
    const int len = HI - LO;
    const int c0  = LO + (len * wv) / 8;
    const int c1  = LO + (len * (wv + 1)) / 8;

    // ---- sentinel-seeded chunk scan (LDS broadcast, branchless chain) ----
#pragma unroll
    for (int k = 0; k < TOPK; ++k) a[k] = sent;
    for (int p0 = c0; p0 < c1; p0 += 64) {
        stage[wv][lane] = sorted[min(p0 + lane, NPTS - 1)];
        const int n = min(64, c1 - p0);
#pragma unroll 2
        for (int t = 0; t < n; ++t) {
            float4 cpt = stage[wv][t];
            float dx = cpt.x - me.x, dy = cpt.y - me.y, dz = cpt.z - me.z;
            float d2 = fmaf(dx, dx, fmaf(dy, dy, dz * dz));
            unsigned key = (__float_as_uint(d2) & MASK14) | (unsigned)(p0 + t);
            if (p0 + t == s) key = 0xFFFFFFFFu;
            chain_insert(a, key);
        }
    }

    // ---- merge 8 chunk lists + smoothness + combine ----
    __syncthreads();   // bound-phase xch reads done; safe to rewrite
#pragma unroll
    for (int k = 0; k < TOPK; ++k) xch[wv][lane][k] = a[k];
    __syncthreads();

    if (wv == 0) {
#pragma unroll
        for (int w = 1; w < 8; ++w)
#pragma unroll
            for (int k = 0; k < TOPK; ++k) chain_insert(a, xch[w][lane][k]);
        const float* wptr = (const float*)sorted;
        float v = 0.0f;
#pragma unroll
        for (int k = 0; k < TOPK; ++k) {
            int j = (int)(a[k] & 0x3FFFu);
            v += fabsf(me.w - wptr[4 * j + 3]);
        }
#pragma unroll
        for (int off = 32; off > 0; off >>= 1) v += __shfl_down(v, off, 64);
        if (lane == 0) atomicAdd(&accum[3], v);
    }

    __syncthreads();
    if (threadIdx.x == 0) {
        __threadfence();
        unsigned tk = atomicAdd(ticket, 1u);
        if (tk == gridDim.x - 1) {
            float sp = atomicAdd(&accum[0], 0.0f);
            float sc = atomicAdd(&accum[1], 0.0f);
            float op = atomicAdd(&accum[2], 0.0f);
            float sm = atomicAdd(&accum[3], 0.0f);
            const float n = (float)NPTS;
            out[0] = 0.01f * (sp / n) + 0.1f * (sm / (n * 10.0f))
                   + sc / (3.0f * n) + op / n;
        }
    }
}

extern "C" void kernel_launch(void* const* d_in, const int* in_sizes, int n_in,
                              void* d_out, int out_size, void* d_ws, size_t ws_size,
                              hipStream_t stream)
{
    const float* pos    = (const float*)d_in[0];
    const float* opac   = (const float*)d_in[1];
    const float* scales = (const float*)d_in[2];
    float* out = (float*)d_out;

    char* ws = (char*)d_ws;
    float*    accum  = (float*)ws;
    unsigned* ticket = (unsigned*)(ws + 16);
    unsigned* hist   = (unsigned*)(ws + 256);
    unsigned* cnt    = (unsigned*)(ws + 65792);
    unsigned* base   = (unsigned*)(ws + 131328);
    int*      cid    = (int*)(ws + 196992);
    float4*   sorted = (float4*)(ws + 262528);

    hipMemsetAsync(ws, 0, 131328, stream);   // accum, ticket, hist, cnt

    setup_kernel  <<<NPTS / 256, 256, 0, stream>>>(pos, opac, scales, accum, hist, cid);
    prefix_cells  <<<1, 1024, 0, stream>>>(hist, base);
    scatter_sorted<<<NPTS / 256, 256, 0, stream>>>(pos, opac, cid, base, cnt, sorted);
    knn_fused     <<<NPTS / 64, 512, 0, stream>>>(sorted, base, accum, ticket, out);
}

// Round 8
// 303.260 us; speedup vs baseline: 2.3635x; 1.0589x over previous
//
#include <hip/hip_runtime.h>
#include <stdint.h>

// N=16384 points, K=10 (fixed by setup_inputs).
#define NPTS   16384
#define TOPK   10
#define NCOL   128
#define NROW   128
#define NCELL  (NCOL * NROW)
#define XMIN   (-5.0f)
#define INVW   (12.8f)
#define MASK14 0xFFFFC000u
#define BOFF   224                 // bound window [gbase-224, gbase+288)
#define NSL    8                   // window slices per group

// ws layout (bytes), [0,131328) zeroed by one memset:
//   0      accum[4] floats; 16 ticket uint
//   256    hist[NCELL] uint
//   65792  cnt[NCELL] uint
//   131328 base[NCELL+1] uint
//   196992 cid[NPTS] int
//   262528 r2m[NPTS] uint          (per-point sentinel key)
//   328064 win[256] uint2          (per-group column-rank window)
//   330112 sorted[NPTS] float4     (x,y,z,opacity) (bx,by)-row-major
//   592256 partial[NSL][NPTS][TOPK] uint  (5.24 MB) -> end 5,835,136

__device__ __forceinline__ unsigned umin_(unsigned a, unsigned b) { return a < b ? a : b; }
__device__ __forceinline__ unsigned umax_(unsigned a, unsigned b) { return a > b ? a : b; }

__device__ __forceinline__ void chain_insert(unsigned (&a)[TOPK], unsigned key) {
#pragma unroll
    for (int k = TOPK - 1; k > 0; --k) a[k] = umin_(umax_(a[k - 1], key), a[k]);
    a[0] = umin_(a[0], key);
}

// ---- fused trivial losses + cell histogram --------------------------------
__global__ __launch_bounds__(256) void setup_kernel(
    const float* __restrict__ pos, const float* __restrict__ opac,
    const float* __restrict__ scales, float* __restrict__ accum,
    unsigned* __restrict__ hist, int* __restrict__ cid)
{
    int i = blockIdx.x * 256 + threadIdx.x;
    float o = opac[i];
    float d = o - 0.5f;
    float s_sp = fabsf(o);
    float s_op = d * d;
    float s_sc = fabsf(scales[3 * i] - 1.0f) + fabsf(scales[3 * i + 1] - 1.0f)
               + fabsf(scales[3 * i + 2] - 1.0f);
    float x = pos[3 * i], y = pos[3 * i + 1];
    int bx = min(max((int)((x - XMIN) * INVW), 0), NCOL - 1);
    int by = min(max((int)((y - XMIN) * INVW), 0), NROW - 1);
    int c = bx * NROW + by;
    cid[i] = c;
    atomicAdd(&hist[c], 1u);
#pragma unroll
    for (int off = 32; off > 0; off >>= 1) {
        s_sp += __shfl_down(s_sp, off, 64);
        s_sc += __shfl_down(s_sc, off, 64);
        s_op += __shfl_down(s_op, off, 64);
    }
    if ((threadIdx.x & 63) == 0) {
        atomicAdd(&accum[0], s_sp);
        atomicAdd(&accum[1], s_sc);
        atomicAdd(&accum[2], s_op);
    }
}

// ---- exclusive prefix over 16384 cells ------------------------------------
__global__ __launch_bounds__(1024) void prefix_cells(
    const unsigned* __restrict__ hist, unsigned* __restrict__ base)
{
    __shared__ unsigned bs[16];
    const int t = threadIdx.x, lane = t & 63, wv = t >> 6;
    unsigned loc[16];
    unsigned run = 0;
#pragma unroll
    for (int k = 0; k < 16; ++k) { loc[k] = hist[t * 16 + k]; run += loc[k]; }
    unsigned inc = run;
#pragma unroll
    for (int off = 1; off < 64; off <<= 1) {
        unsigned v = (unsigned)__shfl_up((int)inc, off, 64);
        if (lane >= off) inc += v;
    }
    if (lane == 63) bs[wv] = inc;
    __syncthreads();
    if (t < 16) {
        unsigned v = bs[t];
        unsigned iv = v;
#pragma unroll
        for (int off = 1; off < 16; off <<= 1) {
            unsigned u = (unsigned)__shfl_up((int)iv, off, 64);
            if (t >= off) iv += u;
        }
        bs[t] = iv - v;
    }
    __syncthreads();
    unsigned acc = bs[wv] + inc - run;
#pragma unroll
    for (int k = 0; k < 16; ++k) { base[t * 16 + k] = acc; acc += loc[k]; }
    if (t == 1023) base[NCELL] = acc;
}

__global__ __launch_bounds__(256) void scatter_sorted(
    const float* __restrict__ pos, const float* __restrict__ opac,
    const int* __restrict__ cid, const unsigned* __restrict__ base,
    unsigned* __restrict__ cnt, float4* __restrict__ sorted)
{
    int i = blockIdx.x * 256 + threadIdx.x;
    int c = cid[i];
    unsigned p = base[c] + atomicAdd(&cnt[c], 1u);
    sorted[p] = make_float4(pos[3 * i], pos[3 * i + 1], pos[3 * i + 2], opac[i]);
}

// ---- bound: per-point sentinel + per-group column window ------------------
// Fixed 512-candidate window split 4x128 across the block's waves (every
// wave owns the same 64 points). Wave0 merges via LDS, derives r_i, and the
// group-union column-rank window [LO,HI).
__global__ __launch_bounds__(256) void knn_bound(
    const float4* __restrict__ sorted, const unsigned* __restrict__ cellbase,
    unsigned* __restrict__ r2m, uint2* __restrict__ win)
{
    __shared__ unsigned xch[4][64][TOPK];
    const int lane  = threadIdx.x & 63;
    const int wv    = threadIdx.x >> 6;
    const int gbase = blockIdx.x * 64;
    const int s     = gbase + lane;
    const float4 me = sorted[s];

    unsigned a[TOPK];
#pragma unroll
    for (int k = 0; k < TOPK; ++k) a[k] = 0xFFFFFFFFu;
    const int bstart = gbase - BOFF + wv * 128;
#pragma unroll 4
    for (int t = 0; t < 128; ++t) {
        int pc = (bstart + t) & (NPTS - 1);        // distinct; wraps
        float4 c = sorted[pc];
        float dx = c.x - me.x, dy = c.y - me.y, dz = c.z - me.z;
        float d2 = fmaf(dx, dx, fmaf(dy, dy, dz * dz));
        unsigned key = (__float_as_uint(d2) & MASK14) | (unsigned)pc;
        if (pc == s) key = 0xFFFFFFFFu;
        chain_insert(a, key);
    }
#pragma unroll
    for (int k = 0; k < TOPK; ++k) xch[wv][lane][k] = a[k];
    __syncthreads();
    if (wv == 0) {
#pragma unroll
        for (int w = 1; w < 4; ++w)
#pragma unroll
            for (int k = 0; k < TOPK; ++k) chain_insert(a, xch[w][lane][k]);
        const unsigned B = a[TOPK - 1];             // valid upper bound key
        r2m[s] = (B & MASK14) + 0x8000u;            // sentinel > true-NN keys
        const float ri = sqrtf(__uint_as_float((B & MASK14) + 0x4000u)) * 1.000001f;
        int bxl = min(max((int)((me.x - ri - XMIN) * INVW), 0), NCOL - 1);
        int bxh = min(max((int)((me.x + ri - XMIN) * INVW), 0), NCOL - 1);
        int lo = (int)cellbase[bxl * NROW];
        int hi = (int)cellbase[(bxh + 1) * NROW];
#pragma unroll
        for (int off = 1; off < 64; off <<= 1) {
            lo = min(lo, __shfl_xor(lo, off, 64));
            hi = max(hi, __shfl_xor(hi, off, 64));
        }
        if (lane == 0) win[blockIdx.x] = make_uint2((unsigned)lo, (unsigned)hi);
    }
}

// ---- scan: one wave per (group, slice) work unit --------------------------
// 2048 uniform-ish blocks -> dispatcher load-balances group-size skew.
// Sentinel-seeded branchless chain over slice candidates via LDS broadcast.
__global__ __launch_bounds__(64) void knn_scan(
    const float4* __restrict__ sorted, const unsigned* __restrict__ r2m,
    const uint2* __restrict__ win, unsigned* __restrict__ partial)
{
    __shared__ float4 stage[64];
    const int lane = threadIdx.x;
    const int g    = blockIdx.x >> 3;
    const int sl   = blockIdx.x & (NSL - 1);
    const int s    = g * 64 + lane;
    const float4 me = sorted[s];
    const unsigned sent = r2m[s];

    const uint2 w = win[g];
    const int LO = (int)w.x, len = (int)w.y - (int)w.x;
    const int c0 = LO + (len * sl) / NSL;
    const int c1 = LO + (len * (sl + 1)) / NSL;

    unsigned a[TOPK];
#pragma unroll
    for (int k = 0; k < TOPK; ++k) a[k] = sent;

    for (int p0 = c0; p0 < c1; p0 += 64) {
        stage[lane] = sorted[min(p0 + lane, NPTS - 1)];
        __syncthreads();
        const int n = min(64, c1 - p0);
#pragma unroll 2
        for (int t = 0; t < n; ++t) {
            float4 cpt = stage[t];
            float dx = cpt.x - me.x, dy = cpt.y - me.y, dz = cpt.z - me.z;
            float d2 = fmaf(dx, dx, fmaf(dy, dy, dz * dz));
            unsigned key = (__float_as_uint(d2) & MASK14) | (unsigned)(p0 + t);
            if (p0 + t == s) key = 0xFFFFFFFFu;
            chain_insert(a, key);
        }
        __syncthreads();
    }

    unsigned* dst = partial + ((size_t)sl * NPTS + s) * TOPK;
#pragma unroll
    for (int k = 0; k < TOPK; ++k) dst[k] = a[k];
}

// ---- merge slices + smoothness + fused combine ----------------------------
__global__ __launch_bounds__(256) void knn_merge(
    const float4* __restrict__ sorted, const unsigned* __restrict__ partial,
    float* __restrict__ accum, unsigned* __restrict__ ticket,
    float* __restrict__ out)
{
    const int s = blockIdx.x * 256 + threadIdx.x;
    unsigned a[TOPK];
#pragma unroll
    for (int k = 0; k < TOPK; ++k) a[k] = 0xFFFFFFFFu;
#pragma unroll
    for (int c = 0; c < NSL; ++c) {
        const unsigned* src = partial + ((size_t)c * NPTS + s) * TOPK;
#pragma unroll
        for (int k = 0; k < TOPK; ++k) chain_insert(a, src[k]);
    }
    const float oi = sorted[s].w;
    const float* wptr = (const float*)sorted;
    float v = 0.0f;
#pragma unroll
    for (int k = 0; k < TOPK; ++k) {
        int j = (int)(a[k] & 0x3FFFu);
        v += fabsf(oi - wptr[4 * j + 3]);
    }
#pragma unroll
    for (int off = 32; off > 0; off >>= 1) v += __shfl_down(v, off, 64);
    if ((threadIdx.x & 63) == 0) atomicAdd(&accum[3], v);

    __syncthreads();
    if (threadIdx.x == 0) {
        __threadfence();
        unsigned tk = atomicAdd(ticket, 1u);
        if (tk == gridDim.x - 1) {
            float sp = atomicAdd(&accum[0], 0.0f);
            float sc = atomicAdd(&accum[1], 0.0f);
            float op = atomicAdd(&accum[2], 0.0f);
            float sm = atomicAdd(&accum[3], 0.0f);
            const float n = (float)NPTS;
            out[0] = 0.01f * (sp / n) + 0.1f * (sm / (n * 10.0f))
                   + sc / (3.0f * n) + op / n;
        }
    }
}

extern "C" void kernel_launch(void* const* d_in, const int* in_sizes, int n_in,
                              void* d_out, int out_size, void* d_ws, size_t ws_size,
                              hipStream_t stream)
{
    const float* pos    = (const float*)d_in[0];
    const float* opac   = (const float*)d_in[1];
    const float* scales = (const float*)d_in[2];
    float* out = (float*)d_out;

    char* ws = (char*)d_ws;
    float*    accum   = (float*)ws;
    unsigned* ticket  = (unsigned*)(ws + 16);
    unsigned* hist    = (unsigned*)(ws + 256);
    unsigned* cnt     = (unsigned*)(ws + 65792);
    unsigned* base    = (unsigned*)(ws + 131328);
    int*      cid     = (int*)(ws + 196992);
    unsigned* r2m     = (unsigned*)(ws + 262528);
    uint2*    win     = (uint2*)(ws + 328064);
    float4*   sorted  = (float4*)(ws + 330112);
    unsigned* partial = (unsigned*)(ws + 592256);

    hipMemsetAsync(ws, 0, 131328, stream);   // accum, ticket, hist, cnt

    setup_kernel  <<<NPTS / 256, 256, 0, stream>>>(pos, opac, scales, accum, hist, cid);
    prefix_cells  <<<1, 1024, 0, stream>>>(hist, base);
    scatter_sorted<<<NPTS / 256, 256, 0, stream>>>(pos, opac, cid, base, cnt, sorted);
    knn_bound     <<<NPTS / 64, 256, 0, stream>>>(sorted, base, r2m, win);
    knn_scan      <<<(NPTS / 64) * NSL, 64, 0, stream>>>(sorted, r2m, win, partial);
    knn_merge     <<<NPTS / 256, 256, 0, stream>>>(sorted, partial, accum, ticket, out);
}